// Round 1
// baseline (328.750 us; speedup 1.0000x reference)
//
#include <hip/hip_runtime.h>
#include <hip/hip_bf16.h>
#include <cstdint>

// Problem constants
#define TOK   64
#define INF   4096
#define OUTF  11008
#define NBLK  172        // OUTF / 64 output-channels per block
#define SPLITK 4
#define KCHUNKS 128      // INF / 32
#define KCPQ  32         // KCHUNKS / SPLITK

using bf16x8  = __attribute__((ext_vector_type(8))) __bf16;
using floatx4 = __attribute__((ext_vector_type(4))) float;

union B8u { uint32_t u[4]; uint4 q; bf16x8 v; };

// pack two fp32 into one dword of two truncated bf16 (elem a = low half)
__device__ __forceinline__ uint32_t hi2(float a, float b) {
    return (__float_as_uint(a) >> 16) | (__float_as_uint(b) & 0xffff0000u);
}
// residual after bf16 truncation (exact in fp32)
__device__ __forceinline__ float losub(float x) {
    return x - __uint_as_float(__float_as_uint(x) & 0xffff0000u);
}

// ---------------------------------------------------------------------------
// k_prep_x: fp32 x[64][4096] -> bf16 hi/lo arrays in MFMA A-fragment order.
// Fragment addressing: ((mt*128 + kc)*64 + lane)*8 + j  where the element is
// x[mt*16 + (lane&15)][kc*32 + (lane>>4)*8 + j]   (16x16x32 A layout, m89)
// ---------------------------------------------------------------------------
__global__ __launch_bounds__(256) void k_prep_x(const float* __restrict__ x,
        unsigned short* __restrict__ xh, unsigned short* __restrict__ xl) {
    int idx  = blockIdx.x * 256 + threadIdx.x;          // 0..262143
    int j    = idx & 7;
    int lane = (idx >> 3) & 63;
    int kc   = (idx >> 9) & 127;
    int mt   = idx >> 16;
    int row  = mt * 16 + (lane & 15);
    int col  = kc * 32 + ((lane >> 4) << 3) + j;
    float v  = x[(size_t)row * INF + col];
    uint32_t u = __float_as_uint(v);
    float lo = losub(v);
    xh[idx] = (unsigned short)(u >> 16);
    xl[idx] = (unsigned short)(__float_as_uint(lo) >> 16);
}

// ---------------------------------------------------------------------------
// k_lora_t: tm[t][r] = sum_k x[t][k] * A[r][k]     (64x16, one wave per dot)
// ---------------------------------------------------------------------------
__global__ __launch_bounds__(64) void k_lora_t(const float* __restrict__ x,
        const float* __restrict__ A, float* __restrict__ tm) {
    int t = blockIdx.x >> 4, r = blockIdx.x & 15, lane = threadIdx.x;
    const float4* xr = (const float4*)(x + (size_t)t * INF);
    const float4* ar = (const float4*)(A + (size_t)r * INF);
    float s = 0.f;
    for (int i = lane; i < INF / 4; i += 64) {
        float4 a = xr[i], b = ar[i];
        s += a.x * b.x + a.y * b.y + a.z * b.z + a.w * b.w;
    }
#pragma unroll
    for (int off = 32; off > 0; off >>= 1) s += __shfl_down(s, off);
    if (lane == 0) tm[t * 16 + r] = s;
}

// ---------------------------------------------------------------------------
// k_main: y = x @ W^T via 16x16x32 bf16 MFMA, fp32 emulated as hi/lo split:
//   x*w ~= xh*wh + xh*wl + xl*wh   (rel err ~2^-15)
// Each wave: 16 output channels x all 64 tokens x K/4.  W streamed from
// global in B-fragment order (8 consecutive fp32 per lane), no LDS.
// ---------------------------------------------------------------------------
template<bool ATOMIC>
__global__ __launch_bounds__(256) void k_main(const float* __restrict__ W,
        const uint4* __restrict__ xh, const uint4* __restrict__ xl,
        const float* __restrict__ scale, float* __restrict__ part,
        float* __restrict__ out) {
    int lane = threadIdx.x & 63;
    int wv   = threadIdx.x >> 6;
    int nb   = blockIdx.x % NBLK;
    int q    = blockIdx.x / NBLK;
    int orow = nb * 64 + wv * 16 + (lane & 15);   // this lane's output channel
    int quad = lane >> 4;

    const float* wp = W + (size_t)orow * INF + q * (KCPQ * 32) + quad * 8;

    floatx4 acc[4] = {};   // 4 token-tiles x 4 fp32

#pragma unroll 2
    for (int kc = 0; kc < KCPQ; ++kc) {
        float4 w0 = *(const float4*)(wp + (size_t)kc * 32);
        float4 w1 = *(const float4*)(wp + (size_t)kc * 32 + 4);
        B8u wh, wl;
        wh.u[0] = hi2(w0.x, w0.y);  wh.u[1] = hi2(w0.z, w0.w);
        wh.u[2] = hi2(w1.x, w1.y);  wh.u[3] = hi2(w1.z, w1.w);
        wl.u[0] = hi2(losub(w0.x), losub(w0.y));
        wl.u[1] = hi2(losub(w0.z), losub(w0.w));
        wl.u[2] = hi2(losub(w1.x), losub(w1.y));
        wl.u[3] = hi2(losub(w1.z), losub(w1.w));

        int base = (q * KCPQ + kc) * 64 + lane;
#pragma unroll
        for (int mt = 0; mt < 4; ++mt) {
            B8u ah, al;
            ah.q = xh[mt * 8192 + base];
            al.q = xl[mt * 8192 + base];
            acc[mt] = __builtin_amdgcn_mfma_f32_16x16x32_bf16(ah.v, wh.v, acc[mt], 0, 0, 0);
            acc[mt] = __builtin_amdgcn_mfma_f32_16x16x32_bf16(ah.v, wl.v, acc[mt], 0, 0, 0);
            acc[mt] = __builtin_amdgcn_mfma_f32_16x16x32_bf16(al.v, wh.v, acc[mt], 0, 0, 0);
        }
    }

    // C/D layout (16x16, m89-verified): col = lane&15 (=o), row = quad*4 + reg
#pragma unroll
    for (int mt = 0; mt < 4; ++mt) {
        int token = mt * 16 + quad * 4;
#pragma unroll
        for (int r = 0; r < 4; ++r) {
            if constexpr (ATOMIC) {
                float sc = scale[orow];
                atomicAdd(&out[(size_t)(token + r) * OUTF + orow], sc * acc[mt][r]);
            } else {
                part[((size_t)q * TOK + token + r) * OUTF + orow] = acc[mt][r];
            }
        }
    }
}

// ---------------------------------------------------------------------------
// k_post: out[t][o] = scale[o]*sum_q part[q][t][o] + sum_r tm[t][r]*B[o][r] + bias[o]
// ---------------------------------------------------------------------------
__global__ __launch_bounds__(256) void k_post(const float* __restrict__ part,
        const float* __restrict__ scale, const float* __restrict__ bias,
        const float* __restrict__ lB, const float* __restrict__ tm,
        float* __restrict__ out) {
    int o = blockIdx.x * 256 + threadIdx.x;
    int t = blockIdx.y;
    if (o >= OUTF) return;
    float s = 0.f;
#pragma unroll
    for (int qq = 0; qq < SPLITK; ++qq)
        s += part[((size_t)qq * TOK + t) * OUTF + o];
    const float4* Br = (const float4*)(lB + (size_t)o * 16);
    const float4* tr = (const float4*)(tm + (size_t)t * 16);
    float l = 0.f;
#pragma unroll
    for (int i = 0; i < 4; ++i) {
        float4 b = Br[i], tt = tr[i];
        l += b.x * tt.x + b.y * tt.y + b.z * tt.z + b.w * tt.w;
    }
    out[(size_t)t * OUTF + o] = s * scale[o] + l + bias[o];
}

// Fallback pre-init for the atomic path: out = lora + bias, main adds scale*y.
__global__ __launch_bounds__(256) void k_pre(const float* __restrict__ bias,
        const float* __restrict__ lB, const float* __restrict__ tm,
        float* __restrict__ out) {
    int o = blockIdx.x * 256 + threadIdx.x;
    int t = blockIdx.y;
    if (o >= OUTF) return;
    const float4* Br = (const float4*)(lB + (size_t)o * 16);
    const float4* tr = (const float4*)(tm + (size_t)t * 16);
    float l = 0.f;
#pragma unroll
    for (int i = 0; i < 4; ++i) {
        float4 b = Br[i], tt = tr[i];
        l += b.x * tt.x + b.y * tt.y + b.z * tt.z + b.w * tt.w;
    }
    out[(size_t)t * OUTF + o] = l + bias[o];
}

extern "C" void kernel_launch(void* const* d_in, const int* in_sizes, int n_in,
                              void* d_out, int out_size, void* d_ws, size_t ws_size,
                              hipStream_t stream) {
    const float* x     = (const float*)d_in[0];
    const float* W     = (const float*)d_in[1];
    const float* scale = (const float*)d_in[2];
    const float* lA    = (const float*)d_in[3];
    const float* lB    = (const float*)d_in[4];
    const float* bias  = (const float*)d_in[5];
    float* out = (float*)d_out;

    char* ws = (char*)d_ws;
    unsigned short* xh = (unsigned short*)(ws);            // 512 KB
    unsigned short* xl = (unsigned short*)(ws + 524288);   // 512 KB
    float* tm   = (float*)(ws + 1048576);                  // 4 KB
    float* part = (float*)(ws + 1052672);                  // SPLITK*64*11008*4 = 11.27 MB
    const size_t need = 1052672 + (size_t)SPLITK * TOK * OUTF * 4;

    k_prep_x<<<1024, 256, 0, stream>>>(x, xh, xl);
    k_lora_t<<<1024, 64, 0, stream>>>(x, lA, tm);

    if (ws_size >= need) {
        k_main<false><<<NBLK * SPLITK, 256, 0, stream>>>(W, (const uint4*)xh,
                (const uint4*)xl, scale, part, out);
        k_post<<<dim3(43, TOK), 256, 0, stream>>>(part, scale, bias, lB, tm, out);
    } else {
        k_pre<<<dim3(43, TOK), 256, 0, stream>>>(bias, lB, tm, out);
        k_main<true><<<NBLK * SPLITK, 256, 0, stream>>>(W, (const uint4*)xh,
                (const uint4*)xl, scale, nullptr, out);
    }
}